// Round 3
// baseline (250.102 us; speedup 1.0000x reference)
//
#include <hip/hip_runtime.h>
#include <hip/hip_bf16.h>

// Graph attention: B=8,H=8,N=1024,d=128. fp32 in/out, bf16 MFMA compute.
// R12: 32x32x16 MFMA rework (halves LDS-read bytes per FLOP, the R11 bottleneck):
//  - S and PV both use mfma_f32_32x32x16_bf16: per wave-iter 16 MFMA + 20 b128
//    LDS reads (was 32 MFMA + 34 reads at 16x16x32 with no K-frag reuse).
//  - 8 waves = 4 row-groups x 2 col-groups over the 128x64 S tile; PV splits
//    the d-range (each wave computes 32 rows x 64 d), P exchanged via LDS.
//  - Ps: [128][64] bf16, chunk^(row&7) swizzle, stride 64 -> conflict-free
//    b128 A-frag reads and b16 writes (bank arithmetic in comments).
//  - adjacency repacked column-major: adjc[kv][row>>5] u32, bit j = row j of
//    that 32-row group. One dword per lane per iter (L2-resident, hidden).
//  - K dbuf + counted vmcnt (A: vmcnt(0), B: vmcnt(2)) + setprio kept (R10/11).
// LDS: 32K Kt dbuf + 16K Vt + 16K Ps = 64 KB -> 2 blocks/CU at (512,4).
// Falls back to the R8 kernel if ws too small.

typedef __bf16 bf16x8 __attribute__((ext_vector_type(8)));
typedef float  f32x4  __attribute__((ext_vector_type(4)));
typedef float  f32x16 __attribute__((ext_vector_type(16)));
typedef unsigned int u32;

#define NSEQ 1024
#define DH   128
#define BN   64
#define NKT  16
#define TILE_ELEMS (BN * DH)           // 8192 bf16 = 16 KB
#define C1 0.1803368801111244f         // 0.125 * log2(e)
#define C2 11.5415603271110070f        // 8 * log2(e)

__device__ __forceinline__ float f4get(const float4& v, int c) {
    return (c == 0) ? v.x : (c == 1) ? v.y : (c == 2) ? v.z : v.w;
}

__device__ __forceinline__ void gload_lds16(const void* g, void* l) {
    __builtin_amdgcn_global_load_lds(
        (const __attribute__((address_space(1))) u32*)g,
        (__attribute__((address_space(3))) u32*)l, 16, 0, 0);
}

// ---------------- pre-pass: fp32 K/V -> swizzled bf16 tiles; adj -> bits ----
__global__ __launch_bounds__(256)
void prepack_kernel(const float* __restrict__ K, const float* __restrict__ V,
                    __bf16* __restrict__ Kws, __bf16* __restrict__ Vws,
                    u32* __restrict__ adjc, const int* __restrict__ adj)
{
    const int tid = threadIdx.x;
    const int id  = blockIdx.x;

    if (id >= 1024) {
        // adjc[kv][rg32] u32: bit j = adj[rg32*32 + j][kv] > 0.
        // 128 blocks: idx = rg32 (low 5 bits) x kv-block (high 2 bits).
        const int idx  = id - 1024;          // 0..127
        const int rg32 = idx & 31;           // row group of 32
        const int kv   = (idx >> 5) * 256 + tid;
        u32 w = 0;
        #pragma unroll
        for (int j = 0; j < 32; ++j)
            w |= (u32)(adj[(size_t)(rg32 * 32 + j) * NSEQ + kv] > 0) << j;
        adjc[(size_t)kv * 32 + rg32] = w;
        return;
    }

    const size_t gbase = (size_t)(id >> 4) * NSEQ * DH + (size_t)(id & 15) * BN * DH;
    __bf16* ko = Kws + (size_t)id * TILE_ELEMS;
    __bf16* vo = Vws + (size_t)id * TILE_ELEMS;

    // K tile 64x128: coalesced (lanes 0..15 cover one row's 128 floats).
    // swizzle low3 of chunk: cs = (c&8)|((c^(r&7))&7)
    #pragma unroll
    for (int p = 0; p < 4; ++p) {
        const int r = p * 16 + (tid >> 4);
        const int c = tid & 15;
        const float* src = K + gbase + (size_t)r * DH + c * 8;
        float4 a = *(const float4*)src;
        float4 b = *(const float4*)(src + 4);
        bf16x8 w;
        w[0]=(__bf16)a.x; w[1]=(__bf16)a.y; w[2]=(__bf16)a.z; w[3]=(__bf16)a.w;
        w[4]=(__bf16)b.x; w[5]=(__bf16)b.y; w[6]=(__bf16)b.z; w[7]=(__bf16)b.w;
        const int cs = (c & 8) | ((c ^ (r & 7)) & 7);
        *(bf16x8*)(ko + r * DH + cs * 8) = w;
    }
    // V tile transposed -> [d][kv] 128x64: row d, 8 chunks of 8 kv; swz c^(d&7)
    {
        const int vkvb = tid >> 5;         // 0..7
        const int vdb  = tid & 31;         // 4 d each
        float4 vr[8];
        #pragma unroll
        for (int rr = 0; rr < 8; ++rr)
            vr[rr] = *(const float4*)(V + gbase + (size_t)(vkvb * 8 + rr) * DH + vdb * 4);
        #pragma unroll
        for (int c = 0; c < 4; ++c) {
            const int d = vdb * 4 + c;
            bf16x8 w;
            #pragma unroll
            for (int j = 0; j < 8; ++j) w[j] = (__bf16)f4get(vr[j], c);
            const int cs = vkvb ^ (d & 7);
            *(bf16x8*)(vo + d * BN + cs * 8) = w;
        }
    }
}

// ---------------- hot kernel: 8-wave 32x32 pipelined flash attention --------
__global__ __launch_bounds__(512, 4)
void attn_fast(const float* __restrict__ Q, const __bf16* __restrict__ Kws,
               const __bf16* __restrict__ Vws, const u32* __restrict__ adjc,
               float* __restrict__ out)
{
    __shared__ __attribute__((aligned(16))) __bf16 Kt[2][TILE_ELEMS]; // 32 KB dbuf
    __shared__ __attribute__((aligned(16))) __bf16 Vt[TILE_ELEMS];    // 16 KB
    __shared__ __attribute__((aligned(16))) __bf16 Ps[128 * BN];      // 16 KB

    const int tid  = threadIdx.x;
    const int wave = tid >> 6;            // 0..7
    const int lane = tid & 63;
    const int l31  = lane & 31;
    const int hi   = lane >> 5;           // 0/1
    const int l7   = lane & 7;
    const int rowg = wave >> 1;           // 0..3: q-rows rowg*32..+31
    const int colg = wave & 1;            // 0..1: kv cols colg*32..+31 (S), d colg*64 (PV)

    const int id = blockIdx.x;            // XCD swizzle (R6-proven)
    const int bh = (id & 7) * 8 + ((id >> 3) & 7);
    const int q0 = (id >> 6) * 128;
    const size_t base  = (size_t)bh * NSEQ * DH;
    const size_t tile0 = (size_t)(bh * NKT) * TILE_ELEMS;

    // ---- Q fragments: A-frag of 32x32x16: row = l31, k = hi*8 + ks*16 ----
    bf16x8 qf[8];
    {
        const float* qrowp = Q + base + (size_t)(q0 + rowg * 32 + l31) * DH + hi * 8;
        #pragma unroll
        for (int ks = 0; ks < 8; ++ks) {
            const float* src = qrowp + ks * 16;
            float4 a = *(const float4*)src;
            float4 b = *(const float4*)(src + 4);
            bf16x8 w;
            w[0]=(__bf16)a.x; w[1]=(__bf16)a.y; w[2]=(__bf16)a.z; w[3]=(__bf16)a.w;
            w[4]=(__bf16)b.x; w[5]=(__bf16)b.y; w[6]=(__bf16)b.z; w[7]=(__bf16)b.w;
            qf[ks] = w;
        }
    }

    // ---- hoisted K B-frag byte offsets (loop-invariant) ----
    // kv row r = colg*32 + l31; chunk c = ks*2 + hi; cs = (c&8)|((c^(r&7))&7)
    int kaddr[8];
    {
        const int r = colg * 32 + l31;
        #pragma unroll
        for (int ks = 0; ks < 8; ++ks) {
            const int c  = ks * 2 + hi;
            const int cs = (c & 8) | ((c ^ (r & 7)) & 7);
            kaddr[ks] = (r * DH + cs * 8) * 2;   // bytes
        }
    }

    // adjc index: column kv = kt*64 + colg*32 + l31, row-group rg32 = q0/32 + rowg
    const size_t ab = (size_t)(colg * 32 + l31) * 32 + (q0 >> 5) + rowg;

    f32x16 o0, o1;
    #pragma unroll
    for (int i = 0; i < 16; ++i) { o0[i] = 0.f; o1[i] = 0.f; }
    float lp[16];
    #pragma unroll
    for (int i = 0; i < 16; ++i) lp[i] = 0.f;

    // ---- prologue: stage K[0] into Kt[0] ----
    #pragma unroll
    for (int j = 0; j < 2; ++j) {
        const int off = wave * 1024 + j * 512;
        gload_lds16(Kws + tile0 + off + lane * 8, &Kt[0][off]);
    }

    for (int kt = 0; kt < NKT; ++kt) {
        // ---- barrier A: own K[kt] loads (only VMEM in flight) retired ----
        __builtin_amdgcn_sched_barrier(0);
        asm volatile("s_waitcnt vmcnt(0)" ::: "memory");
        __builtin_amdgcn_sched_barrier(0);
        __builtin_amdgcn_s_barrier();
        __builtin_amdgcn_sched_barrier(0);

        // ---- adj mask load (1 dword; retires before V/K' via in-order vmcnt)
        const u32 am = adjc[ab + (size_t)kt * 2048];
        __builtin_amdgcn_sched_barrier(0);

        // ---- stage V[kt] (2 VMEM; hidden under S + softmax) ----
        {
            const __bf16* vtile = Vws + tile0 + (size_t)kt * TILE_ELEMS;
            #pragma unroll
            for (int j = 0; j < 2; ++j) {
                const int off = wave * 1024 + j * 512;
                gload_lds16(vtile + off + lane * 8, &Vt[off]);
            }
        }
        __builtin_amdgcn_sched_barrier(0);

        // ---- prefetch K[kt+1] (2 VMEM; in flight across barrier B) ----
        {
            const int ktn = (kt + 1) & (NKT - 1);   // last iter: dead write
            const __bf16* ktile = Kws + tile0 + (size_t)ktn * TILE_ELEMS;
            __bf16* kdst = &Kt[ktn & 1][0];
            #pragma unroll
            for (int j = 0; j < 2; ++j) {
                const int off = wave * 1024 + j * 512;
                gload_lds16(ktile + off + lane * 8, kdst + off);
            }
        }
        __builtin_amdgcn_sched_barrier(0);

        // ---- S = Q K^T : one 32x32 tile per wave, 8 chained MFMA over k=128
        const __bf16* Kc = &Kt[kt & 1][0];
        f32x16 s;
        #pragma unroll
        for (int i = 0; i < 16; ++i) s[i] = 0.f;
        __builtin_amdgcn_s_setprio(1);
        #pragma unroll
        for (int ks = 0; ks < 8; ++ks) {
            bf16x8 bfr = *(const bf16x8*)((const char*)Kc + kaddr[ks]);
            s = __builtin_amdgcn_mfma_f32_32x32x16_bf16(qf[ks], bfr, s, 0, 0, 0);
        }
        __builtin_amdgcn_s_setprio(0);

        // ---- masked softmax; P into Ps[row][col^] (swz chunk^(row&7)) ----
        // C/D: col = colg*32+l31, row = rowg*32 + (reg&3)+8*(reg>>2)+4*hi
        {
            const u32 m2 = am >> (hi * 4);
            const int chunk0 = colg * 4 + (l31 >> 3);
            const int wbase  = (rowg * 32 + 4 * hi) * BN + l7;
            #pragma unroll
            for (int reg = 0; reg < 16; ++reg) {
                const int rlo = (reg & 3) + 8 * (reg >> 2);     // compile-time
                float p = exp2f(s[reg] * C1 - C2);
                p = ((m2 >> rlo) & 1u) ? p : 0.f;
                lp[reg] += p;
                const int swc = chunk0 ^ ((reg & 3) | (hi << 2)); // chunk0^(row&7)
                Ps[wbase + rlo * BN + swc * 8] = (__bf16)p;
            }
        }

        // ---- barrier B: retire V[kt] (keep K[kt+1] in flight), Ps drained ----
        __builtin_amdgcn_sched_barrier(0);
        asm volatile("s_waitcnt vmcnt(2) lgkmcnt(0)" ::: "memory");
        __builtin_amdgcn_sched_barrier(0);
        __builtin_amdgcn_s_barrier();
        __builtin_amdgcn_sched_barrier(0);

        // ---- O += P V : rows rowg*32..+31, d = colg*64..+63 (2 d-tiles) ----
        // A-frag P: row = l31 (+rowg*32), kv = kstep*16 + hi*8; swz chunk^(l7)
        // B-frag V: col d = dtile*32 + l31, kv chunk = kstep*2+hi; swz ^(d&7)=^l7
        __builtin_amdgcn_s_setprio(1);
        #pragma unroll
        for (int kstep = 0; kstep < 4; ++kstep) {
            const int chs = (kstep * 2 + hi) ^ l7;
            bf16x8 pa = *(const bf16x8*)(&Ps[(rowg * 32 + l31) * BN + chs * 8]);
            bf16x8 vf0 = *(const bf16x8*)(&Vt[(l31)      * BN + chs * 8 + colg * 64 * BN]);
            o0 = __builtin_amdgcn_mfma_f32_32x32x16_bf16(pa, vf0, o0, 0, 0, 0);
            bf16x8 vf1 = *(const bf16x8*)(&Vt[(32 + l31) * BN + chs * 8 + colg * 64 * BN]);
            o1 = __builtin_amdgcn_mfma_f32_32x32x16_bf16(pa, vf1, o1, 0, 0, 0);
        }
        __builtin_amdgcn_s_setprio(0);
    }

    // ---- epilogue: row sums across 32 col-lanes, then across the wave pair --
    #pragma unroll
    for (int reg = 0; reg < 16; ++reg) {
        float ls = lp[reg];
        ls += __shfl_xor(ls, 1);
        ls += __shfl_xor(ls, 2);
        ls += __shfl_xor(ls, 4);
        ls += __shfl_xor(ls, 8);
        ls += __shfl_xor(ls, 16);
        lp[reg] = ls;
    }
    __syncthreads();                      // all PV reads of Vt done
    float* Ls = (float*)&Vt[0];           // reuse Vt: [colg][128 rows]
    if (l31 == 0) {
        #pragma unroll
        for (int reg = 0; reg < 16; ++reg) {
            const int row = rowg * 32 + (reg & 3) + 8 * (reg >> 2) + 4 * hi;
            Ls[colg * 128 + row] = lp[reg];
        }
    }
    __syncthreads();
    #pragma unroll
    for (int reg = 0; reg < 16; ++reg) {
        const int row = rowg * 32 + (reg & 3) + 8 * (reg >> 2) + 4 * hi;
        const float ls = Ls[row] + Ls[128 + row];
        const float linv = 1.0f / fmaxf(ls, 1e-30f);
        float* orow = out + base + (size_t)(q0 + row) * DH + colg * 64 + l31;
        orow[0]  = o0[reg] * linv;
        orow[32] = o1[reg] * linv;
    }
}

// ---------------- fallback (R8-proven) if ws too small ----------------------
#define KS_STRIDE 136
#define VT_STRIDE 64
#define PS_STRIDE 72

__global__ __launch_bounds__(256, 4)
void attn_fallback(const float* __restrict__ Q, const float* __restrict__ K,
                   const float* __restrict__ V, const int* __restrict__ adj,
                   float* __restrict__ out)
{
    __shared__ __attribute__((aligned(16))) __bf16 KsP[BN * KS_STRIDE];
    __shared__ __attribute__((aligned(16))) __bf16 Vts[DH * VT_STRIDE];
    const int tid = threadIdx.x;
    const int wave = tid >> 6, lane = tid & 63, n16 = lane & 15, quad = lane >> 4;
    const int id = blockIdx.x;
    const int bh = (id & 7) * 8 + ((id >> 3) & 7);
    const int q0 = (id >> 6) * 64;
    const size_t base = (size_t)bh * NSEQ * DH;
    const int rp = tid >> 4, kcol = (tid & 15) * 8, db = tid & 31, kvb = tid >> 5;
    bf16x8 qf[4];
    #pragma unroll
    for (int ks = 0; ks < 4; ++ks) {
        const float* src = Q + base + (size_t)(q0 + wave * 16 + n16) * DH + ks * 32 + quad * 8;
        float4 a = *(const float4*)src; float4 b = *(const float4*)(src + 4);
        bf16x8 w;
        w[0]=(__bf16)a.x; w[1]=(__bf16)a.y; w[2]=(__bf16)a.z; w[3]=(__bf16)a.w;
        w[4]=(__bf16)b.x; w[5]=(__bf16)b.y; w[6]=(__bf16)b.z; w[7]=(__bf16)b.w;
        qf[ks] = w;
    }
    f32x4 o[8];
    #pragma unroll
    for (int i = 0; i < 8; ++i) o[i] = (f32x4){0.f, 0.f, 0.f, 0.f};
    float lp[4] = {0.f, 0.f, 0.f, 0.f};
    const int qrow = q0 + wave * 16 + quad * 4;
    for (int kt = 0; kt < NKT; ++kt) {
        const int kv0 = kt * BN;
        __syncthreads();
        #pragma unroll
        for (int it = 0; it < 4; ++it) {
            int row = 16 * it + rp;
            const float* src = K + base + (size_t)(kv0 + row) * DH + kcol;
            float4 a = *(const float4*)src; float4 b = *(const float4*)(src + 4);
            bf16x8 w;
            w[0]=(__bf16)a.x; w[1]=(__bf16)a.y; w[2]=(__bf16)a.z; w[3]=(__bf16)a.w;
            w[4]=(__bf16)b.x; w[5]=(__bf16)b.y; w[6]=(__bf16)b.z; w[7]=(__bf16)b.w;
            *(bf16x8*)(&KsP[row * KS_STRIDE + kcol]) = w;
        }
        {
            float4 vreg[8];
            #pragma unroll
            for (int rr = 0; rr < 8; ++rr)
                vreg[rr] = *(const float4*)(V + base + (size_t)(kv0 + kvb * 8 + rr) * DH + db * 4);
            #pragma unroll
            for (int c = 0; c < 4; ++c) {
                bf16x8 w;
                #pragma unroll
                for (int j = 0; j < 8; ++j) w[j] = (__bf16)f4get(vreg[j], c);
                int d = db * 4 + c, s = (d ^ (d >> 3)) & 7;
                *(bf16x8*)(&Vts[d * VT_STRIDE + ((kvb ^ s) << 3)]) = w;
            }
        }
        __syncthreads();
        int am[4][4];
        #pragma unroll
        for (int i = 0; i < 4; ++i)
            #pragma unroll
            for (int t = 0; t < 4; ++t)
                am[i][t] = adj[(size_t)(qrow + i) * NSEQ + kv0 + t * 16 + n16];
        float sc[4][4];
        #pragma unroll
        for (int t = 0; t < 4; ++t) {
            f32x4 acc = (f32x4){0.f, 0.f, 0.f, 0.f};
            #pragma unroll
            for (int ks = 0; ks < 4; ++ks) {
                bf16x8 bfr = *(const bf16x8*)(&KsP[(t * 16 + n16) * KS_STRIDE + ks * 32 + quad * 8]);
                acc = __builtin_amdgcn_mfma_f32_16x16x32_bf16(qf[ks], bfr, acc, 0, 0, 0);
            }
            #pragma unroll
            for (int i = 0; i < 4; ++i) sc[t][i] = acc[i];
        }
        __syncthreads();
        #pragma unroll
        for (int i = 0; i < 4; ++i) {
            const int prow = wave * 16 + quad * 4 + i;
            float rowsum = 0.f;
            #pragma unroll
            for (int t = 0; t < 4; ++t) {
                float p = exp2f(sc[t][i] * C1 - C2);
                p = (am[i][t] > 0) ? p : 0.f;
                rowsum += p;
                KsP[prow * PS_STRIDE + t * 16 + n16] = (__bf16)p;
            }
            lp[i] += rowsum;
        }
        #pragma unroll
        for (int ks = 0; ks < 2; ++ks) {
            bf16x8 pf = *(const bf16x8*)(&KsP[(wave * 16 + n16) * PS_STRIDE + ks * 32 + quad * 8]);
            #pragma unroll
            for (int nt = 0; nt < 8; ++nt) {
                int d = nt * 16 + n16, s = (d ^ (d >> 3)) & 7, kvbr = ks * 4 + quad;
                bf16x8 vf = *(const bf16x8*)(&Vts[d * VT_STRIDE + ((kvbr ^ s) << 3)]);
                o[nt] = __builtin_amdgcn_mfma_f32_16x16x32_bf16(pf, vf, o[nt], 0, 0, 0);
            }
        }
    }
    float linv[4];
    #pragma unroll
    for (int i = 0; i < 4; ++i) {
        float ls = lp[i];
        ls += __shfl_xor(ls, 1); ls += __shfl_xor(ls, 2);
        ls += __shfl_xor(ls, 4); ls += __shfl_xor(ls, 8);
        linv[i] = 1.0f / fmaxf(ls, 1e-30f);
    }
    #pragma unroll
    for (int nt = 0; nt < 8; ++nt)
        #pragma unroll
        for (int i = 0; i < 4; ++i)
            out[base + (size_t)(qrow + i) * DH + nt * 16 + n16] = o[nt][i] * linv[i];
}

extern "C" void kernel_launch(void* const* d_in, const int* in_sizes, int n_in,
                              void* d_out, int out_size, void* d_ws, size_t ws_size,
                              hipStream_t stream) {
    const float* Q   = (const float*)d_in[0];
    const float* K   = (const float*)d_in[1];
    const float* V   = (const float*)d_in[2];
    const int*   adj = (const int*)d_in[3];
    float* out = (float*)d_out;
    const size_t needKV  = (size_t)2 * 64 * NKT * TILE_ELEMS * sizeof(__bf16); // 33.6 MB
    const size_t needAdj = (size_t)NSEQ * 32 * sizeof(u32);                    // 128 KB
    if (ws_size >= needKV + needAdj) {
        __bf16* Kws = (__bf16*)d_ws;
        __bf16* Vws = Kws + (size_t)64 * NKT * TILE_ELEMS;
        u32* adjc = (u32*)(Vws + (size_t)64 * NKT * TILE_ELEMS);
        prepack_kernel<<<1152, 256, 0, stream>>>(K, V, Kws, Vws, adjc, adj);
        attn_fast<<<512, 512, 0, stream>>>(Q, Kws, Vws, adjc, out);
    } else {
        attn_fallback<<<1024, 256, 0, stream>>>(Q, K, V, adj, out);
    }
}

// Round 4
// 219.247 us; speedup vs baseline: 1.1407x; 1.1407x over previous
//
#include <hip/hip_runtime.h>
#include <hip/hip_bf16.h>

// Graph attention: B=8,H=8,N=1024,d=128. fp32 in/out, bf16 MFMA compute.
// R13: R12's 32x32x16 MFMA structure (layouts refcheck-proven in R12) with the
//      spill fixed: __launch_bounds__(512, 2) instead of (512, 4).
//      R12's (512,4) capped arch VGPRs at 64 (observed VGPR_Count=64) while the
//      kernel needs ~70 arch + 48 acc regs -> per-iter scratch spill/fill
//      (FETCH 33->157 MB, WRITE 32.8->80.9 MB, dur 77->130 us). (512,2) gives a
//      128-reg budget: total ~118 fits, 2 blocks/CU retained (LDS 64 KB).
//  - S and PV use mfma_f32_32x32x16_bf16: 16 MFMA + 20 b128 LDS reads per
//    wave-iter (R11 16x16 version: 32 MFMA + 34 reads) -> LDS bytes/FLOP halved.
//  - 8 waves = 4 row-groups x 2 col-groups over the 128x64 S tile; PV splits
//    the d-range (each wave computes 32 rows x 64 d), P exchanged via LDS.
//  - adjacency column-major bitmask: adjc[kv][row>>5] u32 (1 dword/lane/iter).
//  - K dbuf + counted vmcnt (A: vmcnt(0), B: vmcnt(2)) + setprio kept.
// LDS: 32K Kt dbuf + 16K Vt + 16K Ps = 64 KB -> 2 blocks/CU.
// Falls back to the R8 kernel if ws too small.

typedef __bf16 bf16x8 __attribute__((ext_vector_type(8)));
typedef float  f32x4  __attribute__((ext_vector_type(4)));
typedef float  f32x16 __attribute__((ext_vector_type(16)));
typedef unsigned int u32;

#define NSEQ 1024
#define DH   128
#define BN   64
#define NKT  16
#define TILE_ELEMS (BN * DH)           // 8192 bf16 = 16 KB
#define C1 0.1803368801111244f         // 0.125 * log2(e)
#define C2 11.5415603271110070f        // 8 * log2(e)

__device__ __forceinline__ float f4get(const float4& v, int c) {
    return (c == 0) ? v.x : (c == 1) ? v.y : (c == 2) ? v.z : v.w;
}

__device__ __forceinline__ void gload_lds16(const void* g, void* l) {
    __builtin_amdgcn_global_load_lds(
        (const __attribute__((address_space(1))) u32*)g,
        (__attribute__((address_space(3))) u32*)l, 16, 0, 0);
}

// ---------------- pre-pass: fp32 K/V -> swizzled bf16 tiles; adj -> bits ----
__global__ __launch_bounds__(256)
void prepack_kernel(const float* __restrict__ K, const float* __restrict__ V,
                    __bf16* __restrict__ Kws, __bf16* __restrict__ Vws,
                    u32* __restrict__ adjc, const int* __restrict__ adj)
{
    const int tid = threadIdx.x;
    const int id  = blockIdx.x;

    if (id >= 1024) {
        // adjc[kv][rg32] u32: bit j = adj[rg32*32 + j][kv] > 0.
        // 128 blocks: idx = rg32 (low 5 bits) x kv-block (high 2 bits).
        const int idx  = id - 1024;          // 0..127
        const int rg32 = idx & 31;           // row group of 32
        const int kv   = (idx >> 5) * 256 + tid;
        u32 w = 0;
        #pragma unroll
        for (int j = 0; j < 32; ++j)
            w |= (u32)(adj[(size_t)(rg32 * 32 + j) * NSEQ + kv] > 0) << j;
        adjc[(size_t)kv * 32 + rg32] = w;
        return;
    }

    const size_t gbase = (size_t)(id >> 4) * NSEQ * DH + (size_t)(id & 15) * BN * DH;
    __bf16* ko = Kws + (size_t)id * TILE_ELEMS;
    __bf16* vo = Vws + (size_t)id * TILE_ELEMS;

    // K tile 64x128: coalesced (lanes 0..15 cover one row's 128 floats).
    // swizzle low3 of chunk: cs = (c&8)|((c^(r&7))&7)
    #pragma unroll
    for (int p = 0; p < 4; ++p) {
        const int r = p * 16 + (tid >> 4);
        const int c = tid & 15;
        const float* src = K + gbase + (size_t)r * DH + c * 8;
        float4 a = *(const float4*)src;
        float4 b = *(const float4*)(src + 4);
        bf16x8 w;
        w[0]=(__bf16)a.x; w[1]=(__bf16)a.y; w[2]=(__bf16)a.z; w[3]=(__bf16)a.w;
        w[4]=(__bf16)b.x; w[5]=(__bf16)b.y; w[6]=(__bf16)b.z; w[7]=(__bf16)b.w;
        const int cs = (c & 8) | ((c ^ (r & 7)) & 7);
        *(bf16x8*)(ko + r * DH + cs * 8) = w;
    }
    // V tile transposed -> [d][kv] 128x64: row d, 8 chunks of 8 kv; swz c^(d&7)
    {
        const int vkvb = tid >> 5;         // 0..7
        const int vdb  = tid & 31;         // 4 d each
        float4 vr[8];
        #pragma unroll
        for (int rr = 0; rr < 8; ++rr)
            vr[rr] = *(const float4*)(V + gbase + (size_t)(vkvb * 8 + rr) * DH + vdb * 4);
        #pragma unroll
        for (int c = 0; c < 4; ++c) {
            const int d = vdb * 4 + c;
            bf16x8 w;
            #pragma unroll
            for (int j = 0; j < 8; ++j) w[j] = (__bf16)f4get(vr[j], c);
            const int cs = vkvb ^ (d & 7);
            *(bf16x8*)(vo + d * BN + cs * 8) = w;
        }
    }
}

// ---------------- hot kernel: 8-wave 32x32 pipelined flash attention --------
__global__ __launch_bounds__(512, 2)
void attn_fast(const float* __restrict__ Q, const __bf16* __restrict__ Kws,
               const __bf16* __restrict__ Vws, const u32* __restrict__ adjc,
               float* __restrict__ out)
{
    __shared__ __attribute__((aligned(16))) __bf16 Kt[2][TILE_ELEMS]; // 32 KB dbuf
    __shared__ __attribute__((aligned(16))) __bf16 Vt[TILE_ELEMS];    // 16 KB
    __shared__ __attribute__((aligned(16))) __bf16 Ps[128 * BN];      // 16 KB

    const int tid  = threadIdx.x;
    const int wave = tid >> 6;            // 0..7
    const int lane = tid & 63;
    const int l31  = lane & 31;
    const int hi   = lane >> 5;           // 0/1
    const int l7   = lane & 7;
    const int rowg = wave >> 1;           // 0..3: q-rows rowg*32..+31
    const int colg = wave & 1;            // 0..1: kv cols colg*32..+31 (S), d colg*64 (PV)

    const int id = blockIdx.x;            // XCD swizzle (R6-proven)
    const int bh = (id & 7) * 8 + ((id >> 3) & 7);
    const int q0 = (id >> 6) * 128;
    const size_t base  = (size_t)bh * NSEQ * DH;
    const size_t tile0 = (size_t)(bh * NKT) * TILE_ELEMS;

    // ---- Q fragments: A-frag of 32x32x16: row = l31, k = hi*8 + ks*16 ----
    bf16x8 qf[8];
    {
        const float* qrowp = Q + base + (size_t)(q0 + rowg * 32 + l31) * DH + hi * 8;
        #pragma unroll
        for (int ks = 0; ks < 8; ++ks) {
            const float* src = qrowp + ks * 16;
            float4 a = *(const float4*)src;
            float4 b = *(const float4*)(src + 4);
            bf16x8 w;
            w[0]=(__bf16)a.x; w[1]=(__bf16)a.y; w[2]=(__bf16)a.z; w[3]=(__bf16)a.w;
            w[4]=(__bf16)b.x; w[5]=(__bf16)b.y; w[6]=(__bf16)b.z; w[7]=(__bf16)b.w;
            qf[ks] = w;
        }
    }

    // ---- hoisted K B-frag byte offsets (loop-invariant) ----
    // kv row r = colg*32 + l31; chunk c = ks*2 + hi; cs = (c&8)|((c^(r&7))&7)
    int kaddr[8];
    {
        const int r = colg * 32 + l31;
        #pragma unroll
        for (int ks = 0; ks < 8; ++ks) {
            const int c  = ks * 2 + hi;
            const int cs = (c & 8) | ((c ^ (r & 7)) & 7);
            kaddr[ks] = (r * DH + cs * 8) * 2;   // bytes
        }
    }

    // adjc index: column kv = kt*64 + colg*32 + l31, row-group rg32 = q0/32 + rowg
    const size_t ab = (size_t)(colg * 32 + l31) * 32 + (q0 >> 5) + rowg;

    f32x16 o0, o1;
    #pragma unroll
    for (int i = 0; i < 16; ++i) { o0[i] = 0.f; o1[i] = 0.f; }
    float lp[16];
    #pragma unroll
    for (int i = 0; i < 16; ++i) lp[i] = 0.f;

    // ---- prologue: stage K[0] into Kt[0] ----
    #pragma unroll
    for (int j = 0; j < 2; ++j) {
        const int off = wave * 1024 + j * 512;
        gload_lds16(Kws + tile0 + off + lane * 8, &Kt[0][off]);
    }

    for (int kt = 0; kt < NKT; ++kt) {
        // ---- barrier A: own K[kt] loads (only VMEM in flight) retired ----
        __builtin_amdgcn_sched_barrier(0);
        asm volatile("s_waitcnt vmcnt(0)" ::: "memory");
        __builtin_amdgcn_sched_barrier(0);
        __builtin_amdgcn_s_barrier();
        __builtin_amdgcn_sched_barrier(0);

        // ---- adj mask load (1 dword; retires before V/K' via in-order vmcnt)
        const u32 am = adjc[ab + (size_t)kt * 2048];
        __builtin_amdgcn_sched_barrier(0);

        // ---- stage V[kt] (2 VMEM; hidden under S + softmax) ----
        {
            const __bf16* vtile = Vws + tile0 + (size_t)kt * TILE_ELEMS;
            #pragma unroll
            for (int j = 0; j < 2; ++j) {
                const int off = wave * 1024 + j * 512;
                gload_lds16(vtile + off + lane * 8, &Vt[off]);
            }
        }
        __builtin_amdgcn_sched_barrier(0);

        // ---- prefetch K[kt+1] (2 VMEM; in flight across barrier B) ----
        {
            const int ktn = (kt + 1) & (NKT - 1);   // last iter: dead write
            const __bf16* ktile = Kws + tile0 + (size_t)ktn * TILE_ELEMS;
            __bf16* kdst = &Kt[ktn & 1][0];
            #pragma unroll
            for (int j = 0; j < 2; ++j) {
                const int off = wave * 1024 + j * 512;
                gload_lds16(ktile + off + lane * 8, kdst + off);
            }
        }
        __builtin_amdgcn_sched_barrier(0);

        // ---- S = Q K^T : one 32x32 tile per wave, 8 chained MFMA over k=128
        const __bf16* Kc = &Kt[kt & 1][0];
        f32x16 s;
        #pragma unroll
        for (int i = 0; i < 16; ++i) s[i] = 0.f;
        __builtin_amdgcn_s_setprio(1);
        #pragma unroll
        for (int ks = 0; ks < 8; ++ks) {
            bf16x8 bfr = *(const bf16x8*)((const char*)Kc + kaddr[ks]);
            s = __builtin_amdgcn_mfma_f32_32x32x16_bf16(qf[ks], bfr, s, 0, 0, 0);
        }
        __builtin_amdgcn_s_setprio(0);

        // ---- masked softmax; P into Ps[row][col^] (swz chunk^(row&7)) ----
        // C/D: col = colg*32+l31, row = rowg*32 + (reg&3)+8*(reg>>2)+4*hi
        {
            const u32 m2 = am >> (hi * 4);
            const int chunk0 = colg * 4 + (l31 >> 3);
            const int wbase  = (rowg * 32 + 4 * hi) * BN + l7;
            #pragma unroll
            for (int reg = 0; reg < 16; ++reg) {
                const int rlo = (reg & 3) + 8 * (reg >> 2);     // compile-time
                float p = exp2f(s[reg] * C1 - C2);
                p = ((m2 >> rlo) & 1u) ? p : 0.f;
                lp[reg] += p;
                const int swc = chunk0 ^ ((reg & 3) | (hi << 2)); // chunk0^(row&7)
                Ps[wbase + rlo * BN + swc * 8] = (__bf16)p;
            }
        }

        // ---- barrier B: retire V[kt] (keep K[kt+1] in flight), Ps drained ----
        __builtin_amdgcn_sched_barrier(0);
        asm volatile("s_waitcnt vmcnt(2) lgkmcnt(0)" ::: "memory");
        __builtin_amdgcn_sched_barrier(0);
        __builtin_amdgcn_s_barrier();
        __builtin_amdgcn_sched_barrier(0);

        // ---- O += P V : rows rowg*32..+31, d = colg*64..+63 (2 d-tiles) ----
        // A-frag P: row = l31 (+rowg*32), kv = kstep*16 + hi*8; swz chunk^(l7)
        // B-frag V: col d = dtile*32 + l31, kv chunk = kstep*2+hi; swz ^(d&7)=^l7
        __builtin_amdgcn_s_setprio(1);
        #pragma unroll
        for (int kstep = 0; kstep < 4; ++kstep) {
            const int chs = (kstep * 2 + hi) ^ l7;
            bf16x8 pa = *(const bf16x8*)(&Ps[(rowg * 32 + l31) * BN + chs * 8]);
            bf16x8 vf0 = *(const bf16x8*)(&Vt[(l31)      * BN + chs * 8 + colg * 64 * BN]);
            o0 = __builtin_amdgcn_mfma_f32_32x32x16_bf16(pa, vf0, o0, 0, 0, 0);
            bf16x8 vf1 = *(const bf16x8*)(&Vt[(32 + l31) * BN + chs * 8 + colg * 64 * BN]);
            o1 = __builtin_amdgcn_mfma_f32_32x32x16_bf16(pa, vf1, o1, 0, 0, 0);
        }
        __builtin_amdgcn_s_setprio(0);
    }

    // ---- epilogue: row sums across 32 col-lanes, then across the wave pair --
    #pragma unroll
    for (int reg = 0; reg < 16; ++reg) {
        float ls = lp[reg];
        ls += __shfl_xor(ls, 1);
        ls += __shfl_xor(ls, 2);
        ls += __shfl_xor(ls, 4);
        ls += __shfl_xor(ls, 8);
        ls += __shfl_xor(ls, 16);
        lp[reg] = ls;
    }
    __syncthreads();                      // all PV reads of Vt done
    float* Ls = (float*)&Vt[0];           // reuse Vt: [colg][128 rows]
    if (l31 == 0) {
        #pragma unroll
        for (int reg = 0; reg < 16; ++reg) {
            const int row = rowg * 32 + (reg & 3) + 8 * (reg >> 2) + 4 * hi;
            Ls[colg * 128 + row] = lp[reg];
        }
    }
    __syncthreads();
    #pragma unroll
    for (int reg = 0; reg < 16; ++reg) {
        const int row = rowg * 32 + (reg & 3) + 8 * (reg >> 2) + 4 * hi;
        const float ls = Ls[row] + Ls[128 + row];
        const float linv = 1.0f / fmaxf(ls, 1e-30f);
        float* orow = out + base + (size_t)(q0 + row) * DH + colg * 64 + l31;
        orow[0]  = o0[reg] * linv;
        orow[32] = o1[reg] * linv;
    }
}

// ---------------- fallback (R8-proven) if ws too small ----------------------
#define KS_STRIDE 136
#define VT_STRIDE 64
#define PS_STRIDE 72

__global__ __launch_bounds__(256, 4)
void attn_fallback(const float* __restrict__ Q, const float* __restrict__ K,
                   const float* __restrict__ V, const int* __restrict__ adj,
                   float* __restrict__ out)
{
    __shared__ __attribute__((aligned(16))) __bf16 KsP[BN * KS_STRIDE];
    __shared__ __attribute__((aligned(16))) __bf16 Vts[DH * VT_STRIDE];
    const int tid = threadIdx.x;
    const int wave = tid >> 6, lane = tid & 63, n16 = lane & 15, quad = lane >> 4;
    const int id = blockIdx.x;
    const int bh = (id & 7) * 8 + ((id >> 3) & 7);
    const int q0 = (id >> 6) * 64;
    const size_t base = (size_t)bh * NSEQ * DH;
    const int rp = tid >> 4, kcol = (tid & 15) * 8, db = tid & 31, kvb = tid >> 5;
    bf16x8 qf[4];
    #pragma unroll
    for (int ks = 0; ks < 4; ++ks) {
        const float* src = Q + base + (size_t)(q0 + wave * 16 + n16) * DH + ks * 32 + quad * 8;
        float4 a = *(const float4*)src; float4 b = *(const float4*)(src + 4);
        bf16x8 w;
        w[0]=(__bf16)a.x; w[1]=(__bf16)a.y; w[2]=(__bf16)a.z; w[3]=(__bf16)a.w;
        w[4]=(__bf16)b.x; w[5]=(__bf16)b.y; w[6]=(__bf16)b.z; w[7]=(__bf16)b.w;
        qf[ks] = w;
    }
    f32x4 o[8];
    #pragma unroll
    for (int i = 0; i < 8; ++i) o[i] = (f32x4){0.f, 0.f, 0.f, 0.f};
    float lp[4] = {0.f, 0.f, 0.f, 0.f};
    const int qrow = q0 + wave * 16 + quad * 4;
    for (int kt = 0; kt < NKT; ++kt) {
        const int kv0 = kt * BN;
        __syncthreads();
        #pragma unroll
        for (int it = 0; it < 4; ++it) {
            int row = 16 * it + rp;
            const float* src = K + base + (size_t)(kv0 + row) * DH + kcol;
            float4 a = *(const float4*)src; float4 b = *(const float4*)(src + 4);
            bf16x8 w;
            w[0]=(__bf16)a.x; w[1]=(__bf16)a.y; w[2]=(__bf16)a.z; w[3]=(__bf16)a.w;
            w[4]=(__bf16)b.x; w[5]=(__bf16)b.y; w[6]=(__bf16)b.z; w[7]=(__bf16)b.w;
            *(bf16x8*)(&KsP[row * KS_STRIDE + kcol]) = w;
        }
        {
            float4 vreg[8];
            #pragma unroll
            for (int rr = 0; rr < 8; ++rr)
                vreg[rr] = *(const float4*)(V + base + (size_t)(kv0 + kvb * 8 + rr) * DH + db * 4);
            #pragma unroll
            for (int c = 0; c < 4; ++c) {
                bf16x8 w;
                #pragma unroll
                for (int j = 0; j < 8; ++j) w[j] = (__bf16)f4get(vreg[j], c);
                int d = db * 4 + c, s = (d ^ (d >> 3)) & 7;
                *(bf16x8*)(&Vts[d * VT_STRIDE + ((kvb ^ s) << 3)]) = w;
            }
        }
        __syncthreads();
        int am[4][4];
        #pragma unroll
        for (int i = 0; i < 4; ++i)
            #pragma unroll
            for (int t = 0; t < 4; ++t)
                am[i][t] = adj[(size_t)(qrow + i) * NSEQ + kv0 + t * 16 + n16];
        float sc[4][4];
        #pragma unroll
        for (int t = 0; t < 4; ++t) {
            f32x4 acc = (f32x4){0.f, 0.f, 0.f, 0.f};
            #pragma unroll
            for (int ks = 0; ks < 4; ++ks) {
                bf16x8 bfr = *(const bf16x8*)(&KsP[(t * 16 + n16) * KS_STRIDE + ks * 32 + quad * 8]);
                acc = __builtin_amdgcn_mfma_f32_16x16x32_bf16(qf[ks], bfr, acc, 0, 0, 0);
            }
            #pragma unroll
            for (int i = 0; i < 4; ++i) sc[t][i] = acc[i];
        }
        __syncthreads();
        #pragma unroll
        for (int i = 0; i < 4; ++i) {
            const int prow = wave * 16 + quad * 4 + i;
            float rowsum = 0.f;
            #pragma unroll
            for (int t = 0; t < 4; ++t) {
                float p = exp2f(sc[t][i] * C1 - C2);
                p = (am[i][t] > 0) ? p : 0.f;
                rowsum += p;
                KsP[prow * PS_STRIDE + t * 16 + n16] = (__bf16)p;
            }
            lp[i] += rowsum;
        }
        #pragma unroll
        for (int ks = 0; ks < 2; ++ks) {
            bf16x8 pf = *(const bf16x8*)(&KsP[(wave * 16 + n16) * PS_STRIDE + ks * 32 + quad * 8]);
            #pragma unroll
            for (int nt = 0; nt < 8; ++nt) {
                int d = nt * 16 + n16, s = (d ^ (d >> 3)) & 7, kvbr = ks * 4 + quad;
                bf16x8 vf = *(const bf16x8*)(&Vts[d * VT_STRIDE + ((kvbr ^ s) << 3)]);
                o[nt] = __builtin_amdgcn_mfma_f32_16x16x32_bf16(pf, vf, o[nt], 0, 0, 0);
            }
        }
    }
    float linv[4];
    #pragma unroll
    for (int i = 0; i < 4; ++i) {
        float ls = lp[i];
        ls += __shfl_xor(ls, 1); ls += __shfl_xor(ls, 2);
        ls += __shfl_xor(ls, 4); ls += __shfl_xor(ls, 8);
        linv[i] = 1.0f / fmaxf(ls, 1e-30f);
    }
    #pragma unroll
    for (int nt = 0; nt < 8; ++nt)
        #pragma unroll
        for (int i = 0; i < 4; ++i)
            out[base + (size_t)(qrow + i) * DH + nt * 16 + n16] = o[nt][i] * linv[i];
}

extern "C" void kernel_launch(void* const* d_in, const int* in_sizes, int n_in,
                              void* d_out, int out_size, void* d_ws, size_t ws_size,
                              hipStream_t stream) {
    const float* Q   = (const float*)d_in[0];
    const float* K   = (const float*)d_in[1];
    const float* V   = (const float*)d_in[2];
    const int*   adj = (const int*)d_in[3];
    float* out = (float*)d_out;
    const size_t needKV  = (size_t)2 * 64 * NKT * TILE_ELEMS * sizeof(__bf16); // 33.6 MB
    const size_t needAdj = (size_t)NSEQ * 32 * sizeof(u32);                    // 128 KB
    if (ws_size >= needKV + needAdj) {
        __bf16* Kws = (__bf16*)d_ws;
        __bf16* Vws = Kws + (size_t)64 * NKT * TILE_ELEMS;
        u32* adjc = (u32*)(Vws + (size_t)64 * NKT * TILE_ELEMS);
        prepack_kernel<<<1152, 256, 0, stream>>>(K, V, Kws, Vws, adjc, adj);
        attn_fast<<<512, 512, 0, stream>>>(Q, Kws, Vws, adjc, out);
    } else {
        attn_fallback<<<1024, 256, 0, stream>>>(Q, K, V, adj, out);
    }
}

// Round 5
// 207.272 us; speedup vs baseline: 1.2066x; 1.0578x over previous
//
#include <hip/hip_runtime.h>
#include <hip/hip_bf16.h>

// Graph attention: B=8,H=8,N=1024,d=128. fp32 in/out, bf16 MFMA compute.
// R14: 32x32x16 structure (R12/R13, refcheck-proven) squeezed to <=128 total
//      regs/wave so __launch_bounds__(512,4) gives 2 blocks/CU (16 waves/CU):
//      R13 at (512,2) needed ~152 regs -> 1 block/CU (Occupancy 21%, 101us).
//  - lp[16] ELIMINATED: row sums accumulated in PV from the pa fragments
//    (lane covers kv = kstep*16+hi*8+j; lane^32 covers the complement; one
//    __shfl_xor(rs,32) in the epilogue completes the sum). -16 regs, and the
//    5-step shuffle-chain epilogue becomes one LDS broadcast.
//  - kaddr[8] ELIMINATED: K swizzle recomputed inline (r&7==l7). -8 regs.
//  - Register need ~= 48 acc (s,o0,o1) + 32 (qf) + ~25 misc <= 128.
//  - S and PV use mfma_f32_32x32x16_bf16: 16 MFMA + 20 b128 LDS reads per
//    wave-iter; 8 waves = 4 rowg x 2 colg; P exchanged via swizzled LDS.
//  - adjacency column-major bitmask adjc[kv][row>>5] (1 dword/lane/iter).
//  - K dbuf + counted vmcnt (A: vmcnt(0), B: vmcnt(2)) + setprio kept.
// LDS: 32K Kt dbuf + 16K Vt + 16K Ps = 64 KB -> 2 blocks/CU.
// Falls back to the R8 kernel if ws too small.

typedef __bf16 bf16x8 __attribute__((ext_vector_type(8)));
typedef float  f32x4  __attribute__((ext_vector_type(4)));
typedef float  f32x16 __attribute__((ext_vector_type(16)));
typedef unsigned int u32;
typedef u32 u32x4 __attribute__((ext_vector_type(4)));

#define NSEQ 1024
#define DH   128
#define BN   64
#define NKT  16
#define TILE_ELEMS (BN * DH)           // 8192 bf16 = 16 KB
#define C1 0.1803368801111244f         // 0.125 * log2(e)
#define C2 11.5415603271110070f        // 8 * log2(e)

__device__ __forceinline__ float f4get(const float4& v, int c) {
    return (c == 0) ? v.x : (c == 1) ? v.y : (c == 2) ? v.z : v.w;
}

__device__ __forceinline__ void gload_lds16(const void* g, void* l) {
    __builtin_amdgcn_global_load_lds(
        (const __attribute__((address_space(1))) u32*)g,
        (__attribute__((address_space(3))) u32*)l, 16, 0, 0);
}

// ---------------- pre-pass: fp32 K/V -> swizzled bf16 tiles; adj -> bits ----
__global__ __launch_bounds__(256)
void prepack_kernel(const float* __restrict__ K, const float* __restrict__ V,
                    __bf16* __restrict__ Kws, __bf16* __restrict__ Vws,
                    u32* __restrict__ adjc, const int* __restrict__ adj)
{
    const int tid = threadIdx.x;
    const int id  = blockIdx.x;

    if (id >= 1024) {
        // adjc[kv][rg32] u32: bit j = adj[rg32*32 + j][kv] > 0.
        const int idx  = id - 1024;          // 0..127
        const int rg32 = idx & 31;           // row group of 32
        const int kv   = (idx >> 5) * 256 + tid;
        u32 w = 0;
        #pragma unroll
        for (int j = 0; j < 32; ++j)
            w |= (u32)(adj[(size_t)(rg32 * 32 + j) * NSEQ + kv] > 0) << j;
        adjc[(size_t)kv * 32 + rg32] = w;
        return;
    }

    const size_t gbase = (size_t)(id >> 4) * NSEQ * DH + (size_t)(id & 15) * BN * DH;
    __bf16* ko = Kws + (size_t)id * TILE_ELEMS;
    __bf16* vo = Vws + (size_t)id * TILE_ELEMS;

    // K tile 64x128: coalesced; swizzle low3 of chunk: cs = (c&8)|((c^(r&7))&7)
    #pragma unroll
    for (int p = 0; p < 4; ++p) {
        const int r = p * 16 + (tid >> 4);
        const int c = tid & 15;
        const float* src = K + gbase + (size_t)r * DH + c * 8;
        float4 a = *(const float4*)src;
        float4 b = *(const float4*)(src + 4);
        bf16x8 w;
        w[0]=(__bf16)a.x; w[1]=(__bf16)a.y; w[2]=(__bf16)a.z; w[3]=(__bf16)a.w;
        w[4]=(__bf16)b.x; w[5]=(__bf16)b.y; w[6]=(__bf16)b.z; w[7]=(__bf16)b.w;
        const int cs = (c & 8) | ((c ^ (r & 7)) & 7);
        *(bf16x8*)(ko + r * DH + cs * 8) = w;
    }
    // V tile transposed -> [d][kv] 128x64: row d, 8 chunks of 8 kv; swz c^(d&7)
    {
        const int vkvb = tid >> 5;         // 0..7
        const int vdb  = tid & 31;         // 4 d each
        float4 vr[8];
        #pragma unroll
        for (int rr = 0; rr < 8; ++rr)
            vr[rr] = *(const float4*)(V + gbase + (size_t)(vkvb * 8 + rr) * DH + vdb * 4);
        #pragma unroll
        for (int c = 0; c < 4; ++c) {
            const int d = vdb * 4 + c;
            bf16x8 w;
            #pragma unroll
            for (int j = 0; j < 8; ++j) w[j] = (__bf16)f4get(vr[j], c);
            const int cs = vkvb ^ (d & 7);
            *(bf16x8*)(vo + d * BN + cs * 8) = w;
        }
    }
}

// ---------------- hot kernel: 8-wave 32x32 pipelined flash attention --------
__global__ __launch_bounds__(512, 4)
void attn_fast(const float* __restrict__ Q, const __bf16* __restrict__ Kws,
               const __bf16* __restrict__ Vws, const u32* __restrict__ adjc,
               float* __restrict__ out)
{
    __shared__ __attribute__((aligned(16))) __bf16 Kt[2][TILE_ELEMS]; // 32 KB dbuf
    __shared__ __attribute__((aligned(16))) __bf16 Vt[TILE_ELEMS];    // 16 KB
    __shared__ __attribute__((aligned(16))) __bf16 Ps[128 * BN];      // 16 KB

    const int tid  = threadIdx.x;
    const int wave = tid >> 6;            // 0..7
    const int lane = tid & 63;
    const int l31  = lane & 31;
    const int hi   = lane >> 5;           // 0/1
    const int l7   = lane & 7;
    const int rowg = wave >> 1;           // 0..3: q-rows rowg*32..+31
    const int colg = wave & 1;            // 0..1: kv cols colg*32..+31 (S), d colg*64 (PV)

    const int id = blockIdx.x;            // XCD swizzle (R6-proven)
    const int bh = (id & 7) * 8 + ((id >> 3) & 7);
    const int q0 = (id >> 6) * 128;
    const size_t base  = (size_t)bh * NSEQ * DH;
    const size_t tile0 = (size_t)(bh * NKT) * TILE_ELEMS;

    // ---- Q fragments: A-frag of 32x32x16: row = l31, k = hi*8 + ks*16 ----
    bf16x8 qf[8];
    {
        const float* qrowp = Q + base + (size_t)(q0 + rowg * 32 + l31) * DH + hi * 8;
        #pragma unroll
        for (int ks = 0; ks < 8; ++ks) {
            const float* src = qrowp + ks * 16;
            float4 a = *(const float4*)src;
            float4 b = *(const float4*)(src + 4);
            bf16x8 w;
            w[0]=(__bf16)a.x; w[1]=(__bf16)a.y; w[2]=(__bf16)a.z; w[3]=(__bf16)a.w;
            w[4]=(__bf16)b.x; w[5]=(__bf16)b.y; w[6]=(__bf16)b.z; w[7]=(__bf16)b.w;
            qf[ks] = w;
        }
    }

    // adjc index: column kv = kt*64 + colg*32 + l31, row-group rg32 = q0/32 + rowg
    const size_t ab = (size_t)(colg * 32 + l31) * 32 + (q0 >> 5) + rowg;
    // K B-frag base (bytes): kv row r = colg*32 + l31 (note r&7 == l7)
    const int kbase = (colg * 32 + l31) * DH * 2;

    f32x16 o0, o1;
    #pragma unroll
    for (int i = 0; i < 16; ++i) { o0[i] = 0.f; o1[i] = 0.f; }
    float rs = 0.f;                       // row-sum (half-row; completed by shfl)

    // ---- prologue: stage K[0] into Kt[0] ----
    #pragma unroll
    for (int j = 0; j < 2; ++j) {
        const int off = wave * 1024 + j * 512;
        gload_lds16(Kws + tile0 + off + lane * 8, &Kt[0][off]);
    }

    for (int kt = 0; kt < NKT; ++kt) {
        // ---- barrier A: own K[kt] loads (only VMEM in flight) retired ----
        __builtin_amdgcn_sched_barrier(0);
        asm volatile("s_waitcnt vmcnt(0)" ::: "memory");
        __builtin_amdgcn_sched_barrier(0);
        __builtin_amdgcn_s_barrier();
        __builtin_amdgcn_sched_barrier(0);

        // ---- adj mask load (1 dword; first VMEM op of the iter) ----
        const u32 am = adjc[ab + (size_t)kt * 2048];
        __builtin_amdgcn_sched_barrier(0);

        // ---- stage V[kt] (2 VMEM; hidden under S + softmax) ----
        {
            const __bf16* vtile = Vws + tile0 + (size_t)kt * TILE_ELEMS;
            #pragma unroll
            for (int j = 0; j < 2; ++j) {
                const int off = wave * 1024 + j * 512;
                gload_lds16(vtile + off + lane * 8, &Vt[off]);
            }
        }
        __builtin_amdgcn_sched_barrier(0);

        // ---- prefetch K[kt+1] (2 VMEM; in flight across barrier B) ----
        {
            const int ktn = (kt + 1) & (NKT - 1);   // last iter: dead write
            const __bf16* ktile = Kws + tile0 + (size_t)ktn * TILE_ELEMS;
            __bf16* kdst = &Kt[ktn & 1][0];
            #pragma unroll
            for (int j = 0; j < 2; ++j) {
                const int off = wave * 1024 + j * 512;
                gload_lds16(ktile + off + lane * 8, kdst + off);
            }
        }
        __builtin_amdgcn_sched_barrier(0);

        // ---- S = Q K^T : one 32x32 tile per wave, 8 chained MFMA over k=128
        const __bf16* Kc = &Kt[kt & 1][0];
        f32x16 s;
        #pragma unroll
        for (int i = 0; i < 16; ++i) s[i] = 0.f;
        __builtin_amdgcn_s_setprio(1);
        #pragma unroll
        for (int ks = 0; ks < 8; ++ks) {
            const int c  = ks * 2 + hi;
            const int cs = (c & 8) | ((c ^ l7) & 7);   // r&7 == l7
            bf16x8 bfr = *(const bf16x8*)((const char*)Kc + kbase + cs * 16);
            s = __builtin_amdgcn_mfma_f32_32x32x16_bf16(qf[ks], bfr, s, 0, 0, 0);
        }
        __builtin_amdgcn_s_setprio(0);

        // ---- masked softmax; P into Ps[row][col^] (swz chunk^(row&7)) ----
        // C/D: col = colg*32+l31, row = rowg*32 + (reg&3)+8*(reg>>2)+4*hi
        {
            const u32 m2 = am >> (hi * 4);
            const int chunk0 = colg * 4 + (l31 >> 3);
            const int wbase  = (rowg * 32 + 4 * hi) * BN + l7;
            #pragma unroll
            for (int reg = 0; reg < 16; ++reg) {
                const int rlo = (reg & 3) + 8 * (reg >> 2);     // compile-time
                float p = exp2f(s[reg] * C1 - C2);
                p = ((m2 >> rlo) & 1u) ? p : 0.f;
                const int swc = chunk0 ^ ((reg & 3) | (hi << 2)); // chunk0^(row&7)
                Ps[wbase + rlo * BN + swc * 8] = (__bf16)p;
            }
        }

        // ---- barrier B: retire V[kt] (keep K[kt+1] in flight), Ps drained ----
        __builtin_amdgcn_sched_barrier(0);
        asm volatile("s_waitcnt vmcnt(2) lgkmcnt(0)" ::: "memory");
        __builtin_amdgcn_sched_barrier(0);
        __builtin_amdgcn_s_barrier();
        __builtin_amdgcn_sched_barrier(0);

        // ---- O += P V : rows rowg*32..+31, d = colg*64..+63 (2 d-tiles) ----
        // A-frag P: row = rowg*32 + l31, kv = kstep*16 + hi*8; swz chunk^(l7)
        // B-frag V: col d = dtile*32 + l31, kv chunk = kstep*2+hi; swz ^(d&7)=^l7
        // rs: lane sums its 32 of the row's 64 kv (lane^32 has the complement)
        __builtin_amdgcn_s_setprio(1);
        #pragma unroll
        for (int kstep = 0; kstep < 4; ++kstep) {
            const int chs = (kstep * 2 + hi) ^ l7;
            bf16x8 pa = *(const bf16x8*)(&Ps[(rowg * 32 + l31) * BN + chs * 8]);
            bf16x8 vf0 = *(const bf16x8*)(&Vt[(l31)      * BN + chs * 8 + colg * 64 * BN]);
            o0 = __builtin_amdgcn_mfma_f32_32x32x16_bf16(pa, vf0, o0, 0, 0, 0);
            bf16x8 vf1 = *(const bf16x8*)(&Vt[(32 + l31) * BN + chs * 8 + colg * 64 * BN]);
            o1 = __builtin_amdgcn_mfma_f32_32x32x16_bf16(pa, vf1, o1, 0, 0, 0);
            // accumulate row-sum from pa (bf16 -> f32 via shift/mask)
            u32x4 pu = __builtin_bit_cast(u32x4, pa);
            #pragma unroll
            for (int w = 0; w < 4; ++w) {
                const u32 d = pu[w];
                rs += __uint_as_float(d << 16);
                rs += __uint_as_float(d & 0xffff0000u);
            }
        }
        __builtin_amdgcn_s_setprio(0);
    }

    // ---- epilogue: complete row sums, broadcast via LDS, scale + store ----
    rs += __shfl_xor(rs, 32);             // full sum of row rowg*32 + l31
    __syncthreads();                      // all PV reads of Vt done
    float* Ls = (float*)&Vt[0];           // reuse Vt: 128 floats
    if (lane < 32 && colg == 0)
        Ls[rowg * 32 + l31] = rs;
    __syncthreads();
    #pragma unroll
    for (int reg = 0; reg < 16; ++reg) {
        const int row = rowg * 32 + (reg & 3) + 8 * (reg >> 2) + 4 * hi;
        const float linv = 1.0f / fmaxf(Ls[row], 1e-30f);
        float* orow = out + base + (size_t)(q0 + row) * DH + colg * 64 + l31;
        orow[0]  = o0[reg] * linv;
        orow[32] = o1[reg] * linv;
    }
}

// ---------------- fallback (R8-proven) if ws too small ----------------------
#define KS_STRIDE 136
#define VT_STRIDE 64
#define PS_STRIDE 72

__global__ __launch_bounds__(256, 4)
void attn_fallback(const float* __restrict__ Q, const float* __restrict__ K,
                   const float* __restrict__ V, const int* __restrict__ adj,
                   float* __restrict__ out)
{
    __shared__ __attribute__((aligned(16))) __bf16 KsP[BN * KS_STRIDE];
    __shared__ __attribute__((aligned(16))) __bf16 Vts[DH * VT_STRIDE];
    const int tid = threadIdx.x;
    const int wave = tid >> 6, lane = tid & 63, n16 = lane & 15, quad = lane >> 4;
    const int id = blockIdx.x;
    const int bh = (id & 7) * 8 + ((id >> 3) & 7);
    const int q0 = (id >> 6) * 64;
    const size_t base = (size_t)bh * NSEQ * DH;
    const int rp = tid >> 4, kcol = (tid & 15) * 8, db = tid & 31, kvb = tid >> 5;
    bf16x8 qf[4];
    #pragma unroll
    for (int ks = 0; ks < 4; ++ks) {
        const float* src = Q + base + (size_t)(q0 + wave * 16 + n16) * DH + ks * 32 + quad * 8;
        float4 a = *(const float4*)src; float4 b = *(const float4*)(src + 4);
        bf16x8 w;
        w[0]=(__bf16)a.x; w[1]=(__bf16)a.y; w[2]=(__bf16)a.z; w[3]=(__bf16)a.w;
        w[4]=(__bf16)b.x; w[5]=(__bf16)b.y; w[6]=(__bf16)b.z; w[7]=(__bf16)b.w;
        qf[ks] = w;
    }
    f32x4 o[8];
    #pragma unroll
    for (int i = 0; i < 8; ++i) o[i] = (f32x4){0.f, 0.f, 0.f, 0.f};
    float lp[4] = {0.f, 0.f, 0.f, 0.f};
    const int qrow = q0 + wave * 16 + quad * 4;
    for (int kt = 0; kt < NKT; ++kt) {
        const int kv0 = kt * BN;
        __syncthreads();
        #pragma unroll
        for (int it = 0; it < 4; ++it) {
            int row = 16 * it + rp;
            const float* src = K + base + (size_t)(kv0 + row) * DH + kcol;
            float4 a = *(const float4*)src; float4 b = *(const float4*)(src + 4);
            bf16x8 w;
            w[0]=(__bf16)a.x; w[1]=(__bf16)a.y; w[2]=(__bf16)a.z; w[3]=(__bf16)a.w;
            w[4]=(__bf16)b.x; w[5]=(__bf16)b.y; w[6]=(__bf16)b.z; w[7]=(__bf16)b.w;
            *(bf16x8*)(&KsP[row * KS_STRIDE + kcol]) = w;
        }
        {
            float4 vreg[8];
            #pragma unroll
            for (int rr = 0; rr < 8; ++rr)
                vreg[rr] = *(const float4*)(V + base + (size_t)(kv0 + kvb * 8 + rr) * DH + db * 4);
            #pragma unroll
            for (int c = 0; c < 4; ++c) {
                bf16x8 w;
                #pragma unroll
                for (int j = 0; j < 8; ++j) w[j] = (__bf16)f4get(vreg[j], c);
                int d = db * 4 + c, s = (d ^ (d >> 3)) & 7;
                *(bf16x8*)(&Vts[d * VT_STRIDE + ((kvb ^ s) << 3)]) = w;
            }
        }
        __syncthreads();
        int am[4][4];
        #pragma unroll
        for (int i = 0; i < 4; ++i)
            #pragma unroll
            for (int t = 0; t < 4; ++t)
                am[i][t] = adj[(size_t)(qrow + i) * NSEQ + kv0 + t * 16 + n16];
        float sc[4][4];
        #pragma unroll
        for (int t = 0; t < 4; ++t) {
            f32x4 acc = (f32x4){0.f, 0.f, 0.f, 0.f};
            #pragma unroll
            for (int ks = 0; ks < 4; ++ks) {
                bf16x8 bfr = *(const bf16x8*)(&KsP[(t * 16 + n16) * KS_STRIDE + ks * 32 + quad * 8]);
                acc = __builtin_amdgcn_mfma_f32_16x16x32_bf16(qf[ks], bfr, acc, 0, 0, 0);
            }
            #pragma unroll
            for (int i = 0; i < 4; ++i) sc[t][i] = acc[i];
        }
        __syncthreads();
        #pragma unroll
        for (int i = 0; i < 4; ++i) {
            const int prow = wave * 16 + quad * 4 + i;
            float rowsum = 0.f;
            #pragma unroll
            for (int t = 0; t < 4; ++t) {
                float p = exp2f(sc[t][i] * C1 - C2);
                p = (am[i][t] > 0) ? p : 0.f;
                rowsum += p;
                KsP[prow * PS_STRIDE + t * 16 + n16] = (__bf16)p;
            }
            lp[i] += rowsum;
        }
        #pragma unroll
        for (int ks = 0; ks < 2; ++ks) {
            bf16x8 pf = *(const bf16x8*)(&KsP[(wave * 16 + n16) * PS_STRIDE + ks * 32 + quad * 8]);
            #pragma unroll
            for (int nt = 0; nt < 8; ++nt) {
                int d = nt * 16 + n16, s = (d ^ (d >> 3)) & 7, kvbr = ks * 4 + quad;
                bf16x8 vf = *(const bf16x8*)(&Vts[d * VT_STRIDE + ((kvbr ^ s) << 3)]);
                o[nt] = __builtin_amdgcn_mfma_f32_16x16x32_bf16(pf, vf, o[nt], 0, 0, 0);
            }
        }
    }
    float linv[4];
    #pragma unroll
    for (int i = 0; i < 4; ++i) {
        float ls = lp[i];
        ls += __shfl_xor(ls, 1); ls += __shfl_xor(ls, 2);
        ls += __shfl_xor(ls, 4); ls += __shfl_xor(ls, 8);
        linv[i] = 1.0f / fmaxf(ls, 1e-30f);
    }
    #pragma unroll
    for (int nt = 0; nt < 8; ++nt)
        #pragma unroll
        for (int i = 0; i < 4; ++i)
            out[base + (size_t)(qrow + i) * DH + nt * 16 + n16] = o[nt][i] * linv[i];
}

extern "C" void kernel_launch(void* const* d_in, const int* in_sizes, int n_in,
                              void* d_out, int out_size, void* d_ws, size_t ws_size,
                              hipStream_t stream) {
    const float* Q   = (const float*)d_in[0];
    const float* K   = (const float*)d_in[1];
    const float* V   = (const float*)d_in[2];
    const int*   adj = (const int*)d_in[3];
    float* out = (float*)d_out;
    const size_t needKV  = (size_t)2 * 64 * NKT * TILE_ELEMS * sizeof(__bf16); // 33.6 MB
    const size_t needAdj = (size_t)NSEQ * 32 * sizeof(u32);                    // 128 KB
    if (ws_size >= needKV + needAdj) {
        __bf16* Kws = (__bf16*)d_ws;
        __bf16* Vws = Kws + (size_t)64 * NKT * TILE_ELEMS;
        u32* adjc = (u32*)(Vws + (size_t)64 * NKT * TILE_ELEMS);
        prepack_kernel<<<1152, 256, 0, stream>>>(K, V, Kws, Vws, adjc, adj);
        attn_fast<<<512, 512, 0, stream>>>(Q, Kws, Vws, adjc, out);
    } else {
        attn_fallback<<<1024, 256, 0, stream>>>(Q, K, V, adj, out);
    }
}